// Round 3
// baseline (273.097 us; speedup 1.0000x reference)
//
#include <hip/hip_runtime.h>
#include <math.h>

typedef int intx4 __attribute__((ext_vector_type(4)));
typedef int intx8 __attribute__((ext_vector_type(8)));
typedef float floatx4 __attribute__((ext_vector_type(4)));

#define N_ROWS 8192
#define KDIM 1024

// E8M0 scale bytes: 123 -> 2^-4 per side (data pre-scaled by 2^4 each side)
#define SCALE_WORD 0x7B7B7B7B

// order-preserving float->int encoding for atomicMax
__device__ __forceinline__ int fenc(float f) {
  int i = __float_as_int(f);
  return i >= 0 ? i : (i ^ 0x7fffffff);
}
__device__ __forceinline__ float fdec(int e) {
  int b = e >= 0 ? e : (e ^ 0x7fffffff);
  return __int_as_float(b);
}

// fp32 -> OCP e4m3fn, round-to-nearest-even. |f| must be < 448 (guaranteed:
// normalized components *16 are <= ~3).
__device__ __forceinline__ unsigned char f2e4m3(float f) {
  const unsigned u = __float_as_uint(f);
  const unsigned s = (u >> 24) & 0x80u;
  const float af = fabsf(f);
  if (af >= 0.015625f) {  // normal range: exponent >= -6
    const int e = (int)((u >> 23) & 0xff) - 127;
    const unsigned m = u & 0x7fffffu;
    unsigned bits = ((unsigned)(e + 7) << 3) | (m >> 20);
    const unsigned rest = m & 0xfffffu;
    bits += (rest > 0x80000u) || (rest == 0x80000u && (bits & 1u));
    return (unsigned char)(s | bits);
  } else {  // subnormal: quantum 2^-9; rint is RNE
    const int qi = (int)rintf(af * 512.0f);  // 0..8 (8 == 2^-6 normal)
    return (unsigned char)(s | (unsigned)qi);
  }
}

// Fused: one block per row of ex (b < 8192) or ey (b >= 8192).
// Computes 1/||x|| (fp32), writes row normalized*16 as e4m3, inits max slot.
__global__ __launch_bounds__(256) void normalize_kernel(
    const float* __restrict__ ex, const float* __restrict__ ey,
    unsigned char* __restrict__ exn, unsigned char* __restrict__ eyn,
    int* __restrict__ rowmax, int* __restrict__ colmax) {
  const int b = blockIdx.x;
  const int tid = threadIdx.x;
  const float* x;
  unsigned char* out;
  int* mslot;
  int row;
  if (b < N_ROWS) {
    x = ex; out = exn; mslot = rowmax; row = b;
  } else {
    x = ey; out = eyn; mslot = colmax; row = b - N_ROWS;
  }
  const float4* xr = (const float4*)(x + (size_t)row * KDIM);
  float4 v = xr[tid];  // 256 threads * 4 = 1024 elements
  float ss = v.x * v.x + v.y * v.y + v.z * v.z + v.w * v.w;
#pragma unroll
  for (int off = 32; off > 0; off >>= 1) ss += __shfl_down(ss, off, 64);
  __shared__ float sred[4];
  if ((tid & 63) == 0) sred[tid >> 6] = ss;
  __syncthreads();
  const float total = sred[0] + sred[1] + sred[2] + sred[3];
  const float rs = 16.0f * rsqrtf(fmaxf(total, 1e-24f));  // 2^4 pre-scale
  uchar4 o;
  o.x = f2e4m3(v.x * rs);
  o.y = f2e4m3(v.y * rs);
  o.z = f2e4m3(v.z * rs);
  o.w = f2e4m3(v.w * rs);
  ((uchar4*)(out + (size_t)row * KDIM))[tid] = o;
  if (tid == 0) mslot[row] = (int)0x80000000;  // encoded -inf floor
}

// 128x128 tile GEMM (A @ B^T, both row-major K-contiguous e4m3, K=1024 bytes
// per row) using MX-scaled mfma_scale_f32_16x16x128_f8f6f4, fused with
// row-max / col-max reduction into global encoded-int atomics.
//
// LDS: 128 rows x 128 B per matrix per K-step. 16-B chunk c of row r is
// stored at slot c ^ (r&7) to kill ds_read_b128 bank conflicts (2-way only).
// Staging picks the matching global source chunk per lane (global_load_lds
// dest is fixed at wave-base + lane*16). Fragment reads look the true chunk
// up at its swizzled slot, so operand byte content depends only on
// (quad, byte index) — identical mapping for A and B, which is all the
// dot-product pairing requires.
__global__ __launch_bounds__(256) void gemm_max_kernel(
    const unsigned char* __restrict__ A, const unsigned char* __restrict__ B,
    int* __restrict__ rowmax, int* __restrict__ colmax) {
  constexpr int TM = 128, BK = 128, K = KDIM;
  __shared__ __align__(16) unsigned char sA[TM * BK];  // 16 KB
  __shared__ __align__(16) unsigned char sB[TM * BK];  // 16 KB

  const int bm = blockIdx.x, bn = blockIdx.y;
  const int tid = threadIdx.x;
  const int lane = tid & 63, wave = tid >> 6;
  const int wm = wave >> 1, wn = wave & 1;  // 2x2 waves of 64x64
  const int quad = lane >> 4, l16 = lane & 15;
  const int sw7 = l16 & 7;

  const char* Ab = (const char*)(A + (size_t)bm * TM * K);
  const char* Bb = (const char*)(B + (size_t)bn * TM * K);

  floatx4 acc[4][4] = {};

  // Staging geometry: wave w stages rows w*32..w*32+31 of each tile.
  // One global_load_lds: 64 lanes x 16 B = 8 rows (8 chunk-lanes per row).
  const int r0 = wave * 32 + (lane >> 3);                    // lane's dest row (it=0)
  const int src_c16 = (((lane & 7) ^ (lane >> 3)) << 4);     // swizzled source chunk
  const char* gA = Ab + (size_t)r0 * K + src_c16;
  const char* gB = Bb + (size_t)r0 * K + src_c16;
  const int obase_w = wave * 4096;

  for (int k0 = 0; k0 < K; k0 += BK) {
#pragma unroll
    for (int it = 0; it < 4; ++it) {
      const int obase = obase_w + it * 1024;   // wave-uniform LDS byte base
      const size_t gofs = (size_t)k0 + (size_t)it * 8 * K;  // +8 rows per it
      __builtin_amdgcn_global_load_lds(
          (__attribute__((address_space(1))) void*)(gA + gofs),
          (__attribute__((address_space(3))) void*)(((char*)sA) + obase), 16, 0, 0);
      __builtin_amdgcn_global_load_lds(
          (__attribute__((address_space(1))) void*)(gB + gofs),
          (__attribute__((address_space(3))) void*)(((char*)sB) + obase), 16, 0, 0);
    }
    __syncthreads();

    // Fragments: lane (quad,l16) holds row l16's bytes quad*32..quad*32+31,
    // i.e. true chunks {2q, 2q+1}, each at swizzled slot (chunk ^ sw7).
    intx8 aF[4], bF[4];
#pragma unroll
    for (int mi = 0; mi < 4; ++mi) {
      const unsigned char* base = &sA[(wm * 64 + mi * 16 + l16) * BK];
      intx4 lo = *(const intx4*)(base + (((2 * quad + 0) ^ sw7) << 4));
      intx4 hi = *(const intx4*)(base + (((2 * quad + 1) ^ sw7) << 4));
      aF[mi] = (intx8){lo.x, lo.y, lo.z, lo.w, hi.x, hi.y, hi.z, hi.w};
    }
#pragma unroll
    for (int ni = 0; ni < 4; ++ni) {
      const unsigned char* base = &sB[(wn * 64 + ni * 16 + l16) * BK];
      intx4 lo = *(const intx4*)(base + (((2 * quad + 0) ^ sw7) << 4));
      intx4 hi = *(const intx4*)(base + (((2 * quad + 1) ^ sw7) << 4));
      bF[ni] = (intx8){lo.x, lo.y, lo.z, lo.w, hi.x, hi.y, hi.z, hi.w};
    }

#pragma unroll
    for (int mi = 0; mi < 4; ++mi)
#pragma unroll
      for (int ni = 0; ni < 4; ++ni)
        acc[mi][ni] = __builtin_amdgcn_mfma_scale_f32_16x16x128_f8f6f4(
            aF[mi], bF[ni], acc[mi][ni],
            0 /*cbsz: fp8*/, 0 /*blgp: fp8*/,
            0, SCALE_WORD, 0, SCALE_WORD);
    __syncthreads();
  }

  // C/D layout (16x16 shapes, dtype-independent): col = lane&15, row = quad*4+reg.
#pragma unroll
  for (int mi = 0; mi < 4; ++mi) {
#pragma unroll
    for (int r = 0; r < 4; ++r) {
      float v = fmaxf(fmaxf(acc[mi][0][r], acc[mi][1][r]),
                      fmaxf(acc[mi][2][r], acc[mi][3][r]));
#pragma unroll
      for (int m = 1; m < 16; m <<= 1) v = fmaxf(v, __shfl_xor(v, m, 64));
      if (l16 == 0) {
        const int grow = bm * TM + wm * 64 + mi * 16 + quad * 4 + r;
        atomicMax(&rowmax[grow], fenc(v));
      }
    }
  }
#pragma unroll
  for (int ni = 0; ni < 4; ++ni) {
    float v = -3.402823466e38f;
#pragma unroll
    for (int mi = 0; mi < 4; ++mi)
#pragma unroll
      for (int r = 0; r < 4; ++r) v = fmaxf(v, acc[mi][ni][r]);
    v = fmaxf(v, __shfl_xor(v, 16, 64));
    v = fmaxf(v, __shfl_xor(v, 32, 64));
    if (quad == 0) {
      const int gcol = bn * TM + wn * 64 + ni * 16 + l16;
      atomicMax(&colmax[gcol], fenc(v));
    }
  }
}

__global__ __launch_bounds__(1024) void finalize_kernel(
    const int* __restrict__ rowmax, const int* __restrict__ colmax,
    float* __restrict__ out) {
  const int tid = threadIdx.x;
  float s1 = 0.f, s2 = 0.f;
  for (int i = tid; i < N_ROWS; i += 1024) {
    s1 += 1.0f - fdec(rowmax[i]);
    s2 += 1.0f - fdec(colmax[i]);
  }
#pragma unroll
  for (int off = 32; off > 0; off >>= 1) {
    s1 += __shfl_down(s1, off, 64);
    s2 += __shfl_down(s2, off, 64);
  }
  __shared__ float r1[16], r2[16];
  if ((tid & 63) == 0) {
    r1[tid >> 6] = s1;
    r2[tid >> 6] = s2;
  }
  __syncthreads();
  if (tid == 0) {
    const double SIGMA = 0.3;
    const double H_CONST = 0.5 * log(2.0 * 3.14159265358979323846 * SIGMA * SIGMA) + 0.5;
    const float HS = (float)(H_CONST / SIGMA);
    float a1 = 0.f, a2 = 0.f;
#pragma unroll
    for (int w = 0; w < 16; ++w) {
      a1 += r1[w];
      a2 += r2[w];
    }
    out[0] = HS * a1;
    out[1] = HS * a2;
  }
}

extern "C" void kernel_launch(void* const* d_in, const int* in_sizes, int n_in,
                              void* d_out, int out_size, void* d_ws, size_t ws_size,
                              hipStream_t stream) {
  const float* ex = (const float*)d_in[0];
  const float* ey = (const float*)d_in[1];
  float* out = (float*)d_out;
  char* ws = (char*)d_ws;

  unsigned char* exn = (unsigned char*)ws;                                   // 8 MB
  unsigned char* eyn = (unsigned char*)(ws + (size_t)N_ROWS * KDIM);         // 8 MB
  int* rowmax = (int*)(ws + (size_t)N_ROWS * KDIM * 2);                      // 32 KB
  int* colmax = rowmax + N_ROWS;                                             // 32 KB

  normalize_kernel<<<2 * N_ROWS, 256, 0, stream>>>(ex, ey, exn, eyn, rowmax, colmax);
  gemm_max_kernel<<<dim3(64, 64), 256, 0, stream>>>(exn, eyn, rowmax, colmax);
  finalize_kernel<<<1, 1024, 0, stream>>>(rowmax, colmax, out);
}